// Round 1
// baseline (1615.425 us; speedup 1.0000x reference)
//
#include <hip/hip_runtime.h>
#include <hip/hip_bf16.h>
#include <math.h>

// Problem constants (Qwen2MoeAttention, T=2048)
#define TSEQ   2048
#define HID    2048
#define NH     16
#define NKV    4
#define HD     128
#define KVD    512
#define SCALING 0.08838834764831845f   // 1/sqrt(128)
#define LOG2_ROPE_BASE 19.931568569324174f  // log2(1e6)

typedef float f4 __attribute__((ext_vector_type(4), aligned(16)));

// ---------------------------------------------------------------------------
// GEMM: Y[T x OUT] = X[T x 2048] @ dequant(W)[2048 x OUT]
// GPTQ int4: qw[(2048/8) x OUT] packed 8/int32 along input dim,
// scales/zeros [(2048/128) x OUT]; w = (q - zero) * scale.
// Tile: 64 rows x 64 cols per block (256 thr), K-tile 128 = one quant group.
// ---------------------------------------------------------------------------
__global__ __launch_bounds__(256) void gemm_gptq(
    const float* __restrict__ X, const int* __restrict__ qw,
    const float* __restrict__ scales, const int* __restrict__ zeros,
    float* __restrict__ Y, int OUT)
{
    __shared__ __align__(16) float Xs[64][132];  // padded: 16B-aligned rows, low conflict
    __shared__ __align__(16) float Ws[128][64];
    const int tid = threadIdx.x;
    const int br = blockIdx.y, bc = blockIdx.x;
    const int tr = tid >> 4, tc = tid & 15;
    const int colg = bc * 64 + (tid & 63);

    float acc[4][4] = {};

    for (int kt = 0; kt < 16; ++kt) {
        __syncthreads();  // previous iteration's reads complete before overwrite
        // --- stage X tile (64 x 128), float4 coalesced ---
        #pragma unroll
        for (int n = 0; n < 8; ++n) {
            int f = tid + 256 * n;
            int r = f >> 5, c4 = f & 31;
            f4 xv = *(const f4*)(X + (br * 64 + r) * 2048 + kt * 128 + c4 * 4);
            *(f4*)(&Xs[r][c4 * 4]) = xv;
        }
        // --- stage dequantized W tile (128 x 64) ---
        const float sc = scales[kt * OUT + colg];
        const float zp = (float)zeros[kt * OUT + colg];
        #pragma unroll
        for (int n = 0; n < 4; ++n) {
            int pr = n * 4 + (tid >> 6);              // packed row 0..15
            unsigned p = (unsigned)qw[(kt * 16 + pr) * OUT + colg];
            #pragma unroll
            for (int s = 0; s < 8; ++s) {
                Ws[pr * 8 + s][tid & 63] =
                    ((float)((p >> (4 * s)) & 15u) - zp) * sc;
            }
        }
        __syncthreads();
        // --- 4x4 register-blocked FMA over this K-tile ---
        #pragma unroll 8
        for (int k4 = 0; k4 < 32; ++k4) {
            f4 a[4], b[4];
            #pragma unroll
            for (int i = 0; i < 4; ++i)
                a[i] = *(const f4*)(&Xs[tr * 4 + i][k4 * 4]);
            #pragma unroll
            for (int kk = 0; kk < 4; ++kk)
                b[kk] = *(const f4*)(&Ws[k4 * 4 + kk][tc * 4]);
            #pragma unroll
            for (int kk = 0; kk < 4; ++kk)
                #pragma unroll
                for (int i = 0; i < 4; ++i)
                    #pragma unroll
                    for (int j = 0; j < 4; ++j)
                        acc[i][j] += a[i][kk] * b[kk][j];
        }
    }
    // --- epilogue: float4 stores ---
    #pragma unroll
    for (int i = 0; i < 4; ++i) {
        f4 r;
        r[0] = acc[i][0]; r[1] = acc[i][1]; r[2] = acc[i][2]; r[3] = acc[i][3];
        *(f4*)(Y + (br * 64 + tr * 4 + i) * OUT + bc * 64 + tc * 4) = r;
    }
}

// ---------------------------------------------------------------------------
// RoPE (NeoX rotate-half), in-place on q [T,16,128] and k [T,4,128].
// One block per t, 256 threads; thread handles pair-index j = tid&63.
// ---------------------------------------------------------------------------
__global__ __launch_bounds__(256) void rope_kernel(
    const int* __restrict__ pos, float* __restrict__ q, float* __restrict__ k)
{
    const int t = blockIdx.x;
    const int tid = threadIdx.x;
    const int j = tid & 63;
    const float p = (float)pos[t];
    const float inv = exp2f(-(float)j * (LOG2_ROPE_BASE / 64.0f));
    const float fr = p * inv;
    float s, c;
    sincosf(fr, &s, &c);
    // q: 16 heads, 4 per thread-group
    #pragma unroll
    for (int n = 0; n < 4; ++n) {
        int h = (tid >> 6) * 4 + n;
        float* base = q + (size_t)t * 2048 + h * 128;
        float x1 = base[j], x2 = base[j + 64];
        base[j]      = x1 * c - x2 * s;
        base[j + 64] = x2 * c + x1 * s;
    }
    { // k: 4 heads, 1 per thread-group
        int h = tid >> 6;
        float* base = k + (size_t)t * 512 + h * 128;
        float x1 = base[j], x2 = base[j + 64];
        base[j]      = x1 * c - x2 * s;
        base[j + 64] = x2 * c + x1 * s;
    }
}

// ---------------------------------------------------------------------------
// Causal GQA flash attention (f32, online softmax).
// Block: one head x 16 query rows; K/V chunks of 32 staged in LDS.
// Thread (qr = tid>>4, dslice = (tid&15)*8) owns 8 output dims of one row.
// ---------------------------------------------------------------------------
__global__ __launch_bounds__(256) void attn_fwd(
    const int* __restrict__ pos, const float* __restrict__ q,
    const float* __restrict__ k, const float* __restrict__ v,
    float* __restrict__ out)
{
    __shared__ __align__(16) float Qs[16][132];
    __shared__ __align__(16) float Ks[32][132];
    __shared__ __align__(16) float Vs[32][132];
    __shared__ float Ss[16][33];
    __shared__ int   Ps[32];
    const int h   = blockIdx.y;
    const int qb  = blockIdx.x;
    const int kvh = h >> 2;
    const int tid = threadIdx.x;
    const int q0  = qb * 16;

    // stage Q tile (16 x 128)
    #pragma unroll
    for (int n = 0; n < 2; ++n) {
        int f = tid + 256 * n;
        int r = f >> 5, c4 = f & 31;
        *(f4*)(&Qs[r][c4 * 4]) =
            *(const f4*)(q + (q0 + r) * 2048 + h * 128 + c4 * 4);
    }
    const int qr  = tid >> 4;
    const int dsl = (tid & 15) * 8;
    const int myqpos = pos[q0 + qr];

    float m = -1e30f, l = 0.0f;
    f4 o0 = {0.f, 0.f, 0.f, 0.f}, o1 = {0.f, 0.f, 0.f, 0.f};
    const int nk = q0 + 16;  // keys needed: 0..q0+15

    for (int kc = 0; kc * 32 < nk; ++kc) {
        __syncthreads();  // previous chunk fully consumed
        // stage K/V chunk (32 x 128 each)
        #pragma unroll
        for (int n = 0; n < 4; ++n) {
            int f = tid + 256 * n;
            int r = f >> 5, c4 = f & 31;
            int krow = kc * 32 + r;
            *(f4*)(&Ks[r][c4 * 4]) = *(const f4*)(k + krow * 512 + kvh * 128 + c4 * 4);
            *(f4*)(&Vs[r][c4 * 4]) = *(const f4*)(v + krow * 512 + kvh * 128 + c4 * 4);
        }
        if (tid < 32) Ps[tid] = pos[kc * 32 + tid];
        __syncthreads();
        // scores: each thread computes S[qr][tid&15] and S[qr][(tid&15)+16]
        #pragma unroll
        for (int half = 0; half < 2; ++half) {
            int sk = (tid & 15) + half * 16;
            float accs = 0.0f;
            #pragma unroll 8
            for (int c4 = 0; c4 < 32; ++c4) {
                f4 qv = *(const f4*)(&Qs[qr][c4 * 4]);
                f4 kv = *(const f4*)(&Ks[sk][c4 * 4]);
                accs += qv[0] * kv[0] + qv[1] * kv[1] + qv[2] * kv[2] + qv[3] * kv[3];
            }
            Ss[qr][sk] = accs * SCALING;
        }
        __syncthreads();
        // online softmax update for row qr
        float sv[32];
        float cm = -1e30f;
        #pragma unroll
        for (int kk = 0; kk < 32; ++kk) {
            float s_ = Ss[qr][kk];
            if (Ps[kk] > myqpos) s_ = -1e30f;  // causal mask (pre-softmax, as ref)
            sv[kk] = s_;
            cm = fmaxf(cm, s_);
        }
        float mn = fmaxf(m, cm);
        float fs = expf(m - mn);
        o0 *= fs; o1 *= fs;
        float psum = 0.0f;
        #pragma unroll
        for (int kk = 0; kk < 32; ++kk) {
            float pk = expf(sv[kk] - mn);
            psum += pk;
            f4 v0 = *(const f4*)(&Vs[kk][dsl]);
            f4 v1 = *(const f4*)(&Vs[kk][dsl + 4]);
            o0 += pk * v0;
            o1 += pk * v1;
        }
        l = l * fs + psum;
        m = mn;
    }
    const float inv_l = 1.0f / l;
    *(f4*)(out + (q0 + qr) * 2048 + h * 128 + dsl)     = o0 * inv_l;
    *(f4*)(out + (q0 + qr) * 2048 + h * 128 + dsl + 4) = o1 * inv_l;
}

// ---------------------------------------------------------------------------
extern "C" void kernel_launch(void* const* d_in, const int* in_sizes, int n_in,
                              void* d_out, int out_size, void* d_ws, size_t ws_size,
                              hipStream_t stream)
{
    const int*   positions = (const int*)  d_in[0];
    const float* hidden    = (const float*)d_in[1];
    const int*   q_qw = (const int*)  d_in[2];
    const float* q_sc = (const float*)d_in[3];
    const int*   q_zr = (const int*)  d_in[4];
    const int*   k_qw = (const int*)  d_in[5];
    const float* k_sc = (const float*)d_in[6];
    const int*   k_zr = (const int*)  d_in[7];
    const int*   v_qw = (const int*)  d_in[8];
    const float* v_sc = (const float*)d_in[9];
    const int*   v_zr = (const int*)  d_in[10];
    const int*   o_qw = (const int*)  d_in[11];
    const float* o_sc = (const float*)d_in[12];
    const int*   o_zr = (const int*)  d_in[13];
    float* outf = (float*)d_out;

    // workspace layout (f32): q[T,2048] | k[T,512] | v[T,512] | attn[T,2048] = 40 MB
    float* qbuf = (float*)d_ws;
    float* kbuf = qbuf + (size_t)TSEQ * 2048;
    float* vbuf = kbuf + (size_t)TSEQ * 512;
    float* abuf = vbuf + (size_t)TSEQ * 512;

    dim3 blk(256);
    gemm_gptq<<<dim3(32, 32), blk, 0, stream>>>(hidden, q_qw, q_sc, q_zr, qbuf, 2048);
    gemm_gptq<<<dim3(8, 32),  blk, 0, stream>>>(hidden, k_qw, k_sc, k_zr, kbuf, 512);
    gemm_gptq<<<dim3(8, 32),  blk, 0, stream>>>(hidden, v_qw, v_sc, v_zr, vbuf, 512);
    rope_kernel<<<dim3(TSEQ), blk, 0, stream>>>(positions, qbuf, kbuf);
    attn_fwd<<<dim3(TSEQ / 16, NH), blk, 0, stream>>>(positions, qbuf, kbuf, vbuf, abuf);
    gemm_gptq<<<dim3(32, 32), blk, 0, stream>>>(abuf, o_qw, o_sc, o_zr, outf, 2048);
}

// Round 2
// 770.134 us; speedup vs baseline: 2.0976x; 2.0976x over previous
//
#include <hip/hip_runtime.h>
#include <hip/hip_bf16.h>
#include <math.h>

// Problem constants (Qwen2MoeAttention, T=2048)
#define TSEQ   2048
#define HID    2048
#define NH     16
#define NKV    4
#define HD     128
#define KVD    512
#define SCALING 0.08838834764831845f   // 1/sqrt(128)
#define LOG2_ROPE_BASE 19.931568569324174f  // log2(1e6)
#define LOG2E  1.4426950408889634f

typedef float f4 __attribute__((ext_vector_type(4), aligned(16)));
typedef short s8v __attribute__((ext_vector_type(8), aligned(16)));
typedef short s4v __attribute__((ext_vector_type(4), aligned(8)));

__device__ __forceinline__ short f2bf(float x) {
    union { __hip_bfloat16 b; short s; } u;
    u.b = __float2bfloat16(x);
    return u.s;
}

// ---------------------------------------------------------------------------
// GEMM: Y[T x OUT] = X[T x 2048] @ dequant(W)[2048 x OUT]   (unchanged)
// ---------------------------------------------------------------------------
__global__ __launch_bounds__(256) void gemm_gptq(
    const float* __restrict__ X, const int* __restrict__ qw,
    const float* __restrict__ scales, const int* __restrict__ zeros,
    float* __restrict__ Y, int OUT)
{
    __shared__ __align__(16) float Xs[64][132];
    __shared__ __align__(16) float Ws[128][64];
    const int tid = threadIdx.x;
    const int br = blockIdx.y, bc = blockIdx.x;
    const int tr = tid >> 4, tc = tid & 15;
    const int colg = bc * 64 + (tid & 63);

    float acc[4][4] = {};

    for (int kt = 0; kt < 16; ++kt) {
        __syncthreads();
        #pragma unroll
        for (int n = 0; n < 8; ++n) {
            int f = tid + 256 * n;
            int r = f >> 5, c4 = f & 31;
            f4 xv = *(const f4*)(X + (br * 64 + r) * 2048 + kt * 128 + c4 * 4);
            *(f4*)(&Xs[r][c4 * 4]) = xv;
        }
        const float sc = scales[kt * OUT + colg];
        const float zp = (float)zeros[kt * OUT + colg];
        #pragma unroll
        for (int n = 0; n < 4; ++n) {
            int pr = n * 4 + (tid >> 6);
            unsigned p = (unsigned)qw[(kt * 16 + pr) * OUT + colg];
            #pragma unroll
            for (int s = 0; s < 8; ++s) {
                Ws[pr * 8 + s][tid & 63] =
                    ((float)((p >> (4 * s)) & 15u) - zp) * sc;
            }
        }
        __syncthreads();
        #pragma unroll 8
        for (int k4 = 0; k4 < 32; ++k4) {
            f4 a[4], b[4];
            #pragma unroll
            for (int i = 0; i < 4; ++i)
                a[i] = *(const f4*)(&Xs[tr * 4 + i][k4 * 4]);
            #pragma unroll
            for (int kk = 0; kk < 4; ++kk)
                b[kk] = *(const f4*)(&Ws[k4 * 4 + kk][tc * 4]);
            #pragma unroll
            for (int kk = 0; kk < 4; ++kk)
                #pragma unroll
                for (int i = 0; i < 4; ++i)
                    #pragma unroll
                    for (int j = 0; j < 4; ++j)
                        acc[i][j] += a[i][kk] * b[kk][j];
        }
    }
    #pragma unroll
    for (int i = 0; i < 4; ++i) {
        f4 r;
        r[0] = acc[i][0]; r[1] = acc[i][1]; r[2] = acc[i][2]; r[3] = acc[i][3];
        *(f4*)(Y + (br * 64 + tr * 4 + i) * OUT + bc * 64 + tc * 4) = r;
    }
}

// ---------------------------------------------------------------------------
// RoPE (NeoX rotate-half), in-place on q [T,16,128] and k [T,4,128]. (unchanged)
// ---------------------------------------------------------------------------
__global__ __launch_bounds__(256) void rope_kernel(
    const int* __restrict__ pos, float* __restrict__ q, float* __restrict__ k)
{
    const int t = blockIdx.x;
    const int tid = threadIdx.x;
    const int j = tid & 63;
    const float p = (float)pos[t];
    const float inv = exp2f(-(float)j * (LOG2_ROPE_BASE / 64.0f));
    const float fr = p * inv;
    float s, c;
    sincosf(fr, &s, &c);
    #pragma unroll
    for (int n = 0; n < 4; ++n) {
        int h = (tid >> 6) * 4 + n;
        float* base = q + (size_t)t * 2048 + h * 128;
        float x1 = base[j], x2 = base[j + 64];
        base[j]      = x1 * c - x2 * s;
        base[j + 64] = x2 * c + x1 * s;
    }
    {
        int h = tid >> 6;
        float* base = k + (size_t)t * 512 + h * 128;
        float x1 = base[j], x2 = base[j + 64];
        base[j]      = x1 * c - x2 * s;
        base[j + 64] = x2 * c + x1 * s;
    }
}

// ---------------------------------------------------------------------------
// MFMA flash attention (bf16 mfma_f32_16x16x32, f32 accum/softmax).
// Block: 4 waves, one head, 64 q-rows (wave w owns rows q0+w*16..+15).
// KV chunks of 64. K in LDS row-major XOR-swizzled; V in LDS transposed
// (stride 72); P per-wave XOR-swizzled LDS round-trip for the PV A-operand.
// Fragment layouts (m89-verified): A: row=lane&15, k=(lane>>4)*8+j;
// B: col=lane&15, k=(lane>>4)*8+j; D: col=lane&15, row=(lane>>4)*4+reg.
// ---------------------------------------------------------------------------
__global__ __launch_bounds__(256) void attn_mfma(
    const float* __restrict__ q, const float* __restrict__ k,
    const float* __restrict__ v, float* __restrict__ out)
{
    __shared__ __align__(16) short Ks[64 * 128];   // bf16, XOR-swizzled rows
    __shared__ __align__(16) short Vt[128 * 72];   // bf16, transposed V, pad stride 72
    __shared__ __align__(16) short Pl[4][16 * 64]; // per-wave P, XOR-swizzled

    const int tid = threadIdx.x;
    const int l   = tid & 63;
    const int w   = tid >> 6;
    const int l15 = l & 15;
    const int l4  = l >> 4;
    const int h   = blockIdx.y;
    const int kvh = h >> 2;
    const int qb  = (TSEQ / 64 - 1) - blockIdx.x;  // heavy blocks first
    const int q0  = qb * 64;

    // --- Q fragments (scaled, bf16) : lane holds row l15, k = dc*32 + l4*8 + j
    s8v qf[4];
    {
        const float* qrow = q + (size_t)(q0 + w * 16 + l15) * 2048 + h * 128;
        #pragma unroll
        for (int dc = 0; dc < 4; ++dc) {
            const int c0 = dc * 32 + l4 * 8;
            s8v f;
            #pragma unroll
            for (int j = 0; j < 8; ++j) f[j] = f2bf(qrow[c0 + j] * SCALING);
            qf[dc] = f;
        }
    }

    f4 o[8];
    #pragma unroll
    for (int dt = 0; dt < 8; ++dt) o[dt] = (f4){0.f, 0.f, 0.f, 0.f};
    float m[4]    = {-1e30f, -1e30f, -1e30f, -1e30f};
    float lsum[4] = {0.f, 0.f, 0.f, 0.f};

    const int nchunks = qb + 1;
    for (int kc = 0; kc < nchunks; ++kc) {
        const int k0 = kc * 64;
        __syncthreads();   // previous chunk fully consumed
        // --- stage K chunk (64x128 bf16, XOR swizzle ((r&7)<<3) in shorts) ---
        #pragma unroll
        for (int n = 0; n < 8; ++n) {
            int f = tid + 256 * n;
            int r = f >> 5, c4 = f & 31;
            f4 xv = *(const f4*)(k + (size_t)(k0 + r) * 512 + kvh * 128 + c4 * 4);
            s4v b;
            #pragma unroll
            for (int j = 0; j < 4; ++j) b[j] = f2bf(xv[j]);
            *(s4v*)(&Ks[(r * 128 + c4 * 4) ^ ((r & 7) << 3)]) = b;
        }
        // --- stage V chunk transposed: per-thread 4x4 block transpose ---
        #pragma unroll
        for (int n = 0; n < 2; ++n) {
            int bi = tid + 256 * n;
            int rb = bi & 15, cb = bi >> 4;    // rb: row block (x4), cb: col block (x4)
            const float* vb = v + (size_t)(k0 + rb * 4) * 512 + kvh * 128 + cb * 4;
            f4 r0 = *(const f4*)(vb);
            f4 r1 = *(const f4*)(vb + 512);
            f4 r2 = *(const f4*)(vb + 1024);
            f4 r3 = *(const f4*)(vb + 1536);
            #pragma unroll
            for (int j = 0; j < 4; ++j) {
                s4v c;
                c[0] = f2bf(r0[j]); c[1] = f2bf(r1[j]);
                c[2] = f2bf(r2[j]); c[3] = f2bf(r3[j]);
                *(s4v*)(&Vt[(cb * 4 + j) * 72 + rb * 4]) = c;
            }
        }
        __syncthreads();   // staging visible

        // diagonal-chunk tile skipping: wave w needs k-cols < (w+1)*16
        int kcm = 2, ntc = 4;
        if (kc == qb) { kcm = (w >= 2) ? 2 : 1; ntc = 2 * kcm; }

        // --- QK^T: S[16 q][64 k] per wave, 16x16 tiles ---
        f4 sA[4];
        #pragma unroll
        for (int nt = 0; nt < 4; ++nt) {
            if (nt < ntc) {
                f4 acc = (f4){0.f, 0.f, 0.f, 0.f};
                #pragma unroll
                for (int dc = 0; dc < 4; ++dc) {
                    s8v kf = *(const s8v*)(
                        &Ks[((nt * 16 + l15) * 128 + dc * 32 + l4 * 8) ^ ((l15 & 7) << 3)]);
                    acc = __builtin_amdgcn_mfma_f32_16x16x32_bf16(qf[dc], kf, acc, 0, 0, 0);
                }
                sA[nt] = acc;
            } else {
                sA[nt] = (f4){-1e30f, -1e30f, -1e30f, -1e30f};
            }
        }
        // causal mask on diagonal chunk: k_in_tile > q_in_tile
        if (kc == qb) {
            #pragma unroll
            for (int nt = 0; nt < 4; ++nt)
                #pragma unroll
                for (int r = 0; r < 4; ++r)
                    if (nt * 16 + l15 > w * 16 + l4 * 4 + r) sA[nt][r] = -1e30f;
        }

        // --- online softmax (rows live in regs r, cols across 16 lanes) ---
        float scale_[4];
        #pragma unroll
        for (int r = 0; r < 4; ++r) {
            float mr = fmaxf(fmaxf(sA[0][r], sA[1][r]), fmaxf(sA[2][r], sA[3][r]));
            #pragma unroll
            for (int msk = 1; msk < 16; msk <<= 1)
                mr = fmaxf(mr, __shfl_xor(mr, msk, 64));
            float mn = fmaxf(m[r], mr);
            scale_[r] = exp2f((m[r] - mn) * LOG2E);
            m[r] = mn;
        }
        float ps[4] = {0.f, 0.f, 0.f, 0.f};
        f4 pv[4];
        #pragma unroll
        for (int nt = 0; nt < 4; ++nt) {
            #pragma unroll
            for (int r = 0; r < 4; ++r) {
                float p = exp2f((sA[nt][r] - m[r]) * LOG2E);
                pv[nt][r] = p;
                ps[r] += p;
            }
        }
        #pragma unroll
        for (int r = 0; r < 4; ++r) {
            float s_ = ps[r];
            #pragma unroll
            for (int msk = 1; msk < 16; msk <<= 1)
                s_ += __shfl_xor(s_, msk, 64);
            lsum[r] = lsum[r] * scale_[r] + s_;
        }
        // --- write P (bf16) to per-wave LDS (no barrier: same-wave dep) ---
        #pragma unroll
        for (int nt = 0; nt < 4; ++nt) {
            if (nt < ntc) {
                #pragma unroll
                for (int r = 0; r < 4; ++r) {
                    int row = l4 * 4 + r, col = nt * 16 + l15;
                    Pl[w][(row * 64 + col) ^ ((row & 7) << 3)] = f2bf(pv[nt][r]);
                }
            }
        }
        // --- rescale O ---
        #pragma unroll
        for (int dt = 0; dt < 8; ++dt)
            #pragma unroll
            for (int r = 0; r < 4; ++r) o[dt][r] *= scale_[r];
        // --- PV: O[16 q][128 d] += P[16][64] * V[64][128] ---
        #pragma unroll
        for (int kcc = 0; kcc < 2; ++kcc) {
            if (kcc < kcm) {
                s8v pf = *(const s8v*)(
                    &Pl[w][(l15 * 64 + kcc * 32 + l4 * 8) ^ ((l15 & 7) << 3)]);
                #pragma unroll
                for (int dt = 0; dt < 8; ++dt) {
                    s8v vf = *(const s8v*)(&Vt[(dt * 16 + l15) * 72 + kcc * 32 + l4 * 8]);
                    o[dt] = __builtin_amdgcn_mfma_f32_16x16x32_bf16(pf, vf, o[dt], 0, 0, 0);
                }
            }
        }
    }

    // --- epilogue: O / l ---
    float inv[4];
    #pragma unroll
    for (int r = 0; r < 4; ++r) inv[r] = 1.0f / lsum[r];
    #pragma unroll
    for (int dt = 0; dt < 8; ++dt)
        #pragma unroll
        for (int r = 0; r < 4; ++r)
            out[(size_t)(q0 + w * 16 + l4 * 4 + r) * 2048 + h * 128 + dt * 16 + l15] =
                o[dt][r] * inv[r];
}

// ---------------------------------------------------------------------------
extern "C" void kernel_launch(void* const* d_in, const int* in_sizes, int n_in,
                              void* d_out, int out_size, void* d_ws, size_t ws_size,
                              hipStream_t stream)
{
    const int*   positions = (const int*)  d_in[0];
    const float* hidden    = (const float*)d_in[1];
    const int*   q_qw = (const int*)  d_in[2];
    const float* q_sc = (const float*)d_in[3];
    const int*   q_zr = (const int*)  d_in[4];
    const int*   k_qw = (const int*)  d_in[5];
    const float* k_sc = (const float*)d_in[6];
    const int*   k_zr = (const int*)  d_in[7];
    const int*   v_qw = (const int*)  d_in[8];
    const float* v_sc = (const float*)d_in[9];
    const int*   v_zr = (const int*)  d_in[10];
    const int*   o_qw = (const int*)  d_in[11];
    const float* o_sc = (const float*)d_in[12];
    const int*   o_zr = (const int*)  d_in[13];
    float* outf = (float*)d_out;

    // workspace layout (f32): q[T,2048] | k[T,512] | v[T,512] | attn[T,2048]
    float* qbuf = (float*)d_ws;
    float* kbuf = qbuf + (size_t)TSEQ * 2048;
    float* vbuf = kbuf + (size_t)TSEQ * 512;
    float* abuf = vbuf + (size_t)TSEQ * 512;

    dim3 blk(256);
    gemm_gptq<<<dim3(32, 32), blk, 0, stream>>>(hidden, q_qw, q_sc, q_zr, qbuf, 2048);
    gemm_gptq<<<dim3(8, 32),  blk, 0, stream>>>(hidden, k_qw, k_sc, k_zr, kbuf, 512);
    gemm_gptq<<<dim3(8, 32),  blk, 0, stream>>>(hidden, v_qw, v_sc, v_zr, vbuf, 512);
    rope_kernel<<<dim3(TSEQ), blk, 0, stream>>>(positions, qbuf, kbuf);
    attn_mfma<<<dim3(TSEQ / 64, NH), blk, 0, stream>>>(qbuf, kbuf, vbuf, abuf);
    gemm_gptq<<<dim3(32, 32), blk, 0, stream>>>(abuf, o_qw, o_sc, o_zr, outf, 2048);
}

// Round 3
// 259.318 us; speedup vs baseline: 6.2295x; 2.9698x over previous
//
#include <hip/hip_runtime.h>
#include <hip/hip_bf16.h>
#include <math.h>

// Problem constants (Qwen2MoeAttention, T=2048)
#define TSEQ   2048
#define HID    2048
#define NH     16
#define NKV    4
#define HD     128
#define KVD    512
#define SCALING 0.08838834764831845f   // 1/sqrt(128)
#define LOG2_ROPE_BASE 19.931568569324174f  // log2(1e6)
#define LOG2E  1.4426950408889634f

typedef float f4 __attribute__((ext_vector_type(4), aligned(16)));
typedef short s8v __attribute__((ext_vector_type(8), aligned(16)));
typedef short s4v __attribute__((ext_vector_type(4), aligned(8)));

__device__ __forceinline__ short f2bf(float x) {
    union { __hip_bfloat16 b; short s; } u;
    u.b = __float2bfloat16(x);
    return u.s;
}

// ---------------------------------------------------------------------------
// f32 -> bf16 bulk convert (hidden_states), 8 elems/thread
// ---------------------------------------------------------------------------
__global__ __launch_bounds__(256) void f32_to_bf16(
    const float* __restrict__ in, short* __restrict__ out)
{
    const int i = (blockIdx.x * 256 + threadIdx.x) * 8;
    f4 a = *(const f4*)(in + i);
    f4 b = *(const f4*)(in + i + 4);
    s8v v;
    v[0] = f2bf(a[0]); v[1] = f2bf(a[1]); v[2] = f2bf(a[2]); v[3] = f2bf(a[3]);
    v[4] = f2bf(b[0]); v[5] = f2bf(b[1]); v[6] = f2bf(b[2]); v[7] = f2bf(b[3]);
    *(s8v*)(out + i) = v;
}

// ---------------------------------------------------------------------------
// MFMA GPTQ GEMM: Y[2048 x OUT] f32 = Xbf16[2048 x 2048] @ dequant(W)
// BK=64, 256 threads = 4 waves in 2x2; wave tile (BM/2 x BN/2).
// A: LDS [BM][64] bf16 XOR-swizzled; B: LDS [BN][64] (B^T) XOR-swizzled,
// dequantized int4 -> bf16 at stage time. 2-barrier K-loop (m97 structure).
// Fragment layouts (m89): A row=lane&15, k=(lane>>4)*8+j; B col=lane&15,
// same k; D col=lane&15, row=(lane>>4)*4+reg.
// ---------------------------------------------------------------------------
template<int BM, int BN>
__global__ __launch_bounds__(256) void gemm_gptq_mfma(
    const short* __restrict__ X, const int* __restrict__ qw,
    const float* __restrict__ scales, const int* __restrict__ zeros,
    float* __restrict__ Y, int OUT)
{
    constexpr int WM = BM / 2, WN = BN / 2, FM = WM / 16, FN = WN / 16;
    __shared__ __align__(16) short As[BM * 64];
    __shared__ __align__(16) short Bs[BN * 64];
    const int tid = threadIdx.x;
    const int l = tid & 63, w = tid >> 6;
    const int l15 = l & 15, l4 = l >> 4;
    const int wr = w >> 1, wc = w & 1;
    const int br = blockIdx.y, bc = blockIdx.x;

    const int colB = tid % BN;                 // B-staging column (0..BN-1)
    const int colg = bc * BN + colB;           // global output column
    const int prb  = (tid / BN) * (BN / 32);   // packed-row base (of 8)

    f4 acc[FM][FN] = {};

    for (int kt = 0; kt < 32; ++kt) {
        __syncthreads();
        // --- stage A (BM x 64 bf16), reg-staged with XOR swizzle ---
        #pragma unroll
        for (int n = 0; n < BM / 32; ++n) {
            int f = tid + 256 * n;
            int r = f >> 3, c8 = f & 7;
            s8v av = *(const s8v*)(X + (size_t)(br * BM + r) * 2048 + kt * 64 + c8 * 8);
            *(s8v*)(&As[r * 64 + ((c8 * 8) ^ ((r & 7) << 3))]) = av;
        }
        // --- stage B: dequant int4 -> bf16, store B^T [BN][64] swizzled ---
        {
            const int g = kt >> 1;   // quant group (128 wide in K)
            const float sc = scales[g * OUT + colg];
            const float zf = (float)zeros[g * OUT + colg];
            #pragma unroll
            for (int n = 0; n < BN / 32; ++n) {
                int pr = prb + n;
                unsigned p = (unsigned)qw[(kt * 8 + pr) * OUT + colg];
                s8v bv;
                #pragma unroll
                for (int s = 0; s < 8; ++s) {
                    float qv = (float)((p >> (4 * s)) & 15u);
                    bv[s] = f2bf((qv - zf) * sc);
                }
                *(s8v*)(&Bs[colB * 64 + ((pr * 8) ^ ((colB & 7) << 3))]) = bv;
            }
        }
        __syncthreads();
        // --- MFMA over the K-tile (two K=32 slices) ---
        #pragma unroll
        for (int ks = 0; ks < 2; ++ks) {
            s8v a[FM], b[FN];
            #pragma unroll
            for (int m_ = 0; m_ < FM; ++m_) {
                int row = wr * WM + m_ * 16 + l15;
                a[m_] = *(const s8v*)(&As[row * 64 + ((ks * 32 + l4 * 8) ^ ((row & 7) << 3))]);
            }
            #pragma unroll
            for (int n_ = 0; n_ < FN; ++n_) {
                int col = wc * WN + n_ * 16 + l15;
                b[n_] = *(const s8v*)(&Bs[col * 64 + ((ks * 32 + l4 * 8) ^ ((col & 7) << 3))]);
            }
            #pragma unroll
            for (int m_ = 0; m_ < FM; ++m_)
                #pragma unroll
                for (int n_ = 0; n_ < FN; ++n_)
                    acc[m_][n_] = __builtin_amdgcn_mfma_f32_16x16x32_bf16(
                        a[m_], b[n_], acc[m_][n_], 0, 0, 0);
        }
    }
    // --- epilogue: f32 stores (D: col=l15, row=l4*4+r) ---
    #pragma unroll
    for (int m_ = 0; m_ < FM; ++m_)
        #pragma unroll
        for (int n_ = 0; n_ < FN; ++n_)
            #pragma unroll
            for (int r = 0; r < 4; ++r)
                Y[(size_t)(br * BM + wr * WM + m_ * 16 + l4 * 4 + r) * OUT
                  + bc * BN + wc * WN + n_ * 16 + l15] = acc[m_][n_][r];
}

// ---------------------------------------------------------------------------
// RoPE (NeoX rotate-half), in-place on q [T,16,128] and k [T,4,128].
// ---------------------------------------------------------------------------
__global__ __launch_bounds__(256) void rope_kernel(
    const int* __restrict__ pos, float* __restrict__ q, float* __restrict__ k)
{
    const int t = blockIdx.x;
    const int tid = threadIdx.x;
    const int j = tid & 63;
    const float p = (float)pos[t];
    const float inv = exp2f(-(float)j * (LOG2_ROPE_BASE / 64.0f));
    const float fr = p * inv;
    float s, c;
    sincosf(fr, &s, &c);
    #pragma unroll
    for (int n = 0; n < 4; ++n) {
        int h = (tid >> 6) * 4 + n;
        float* base = q + (size_t)t * 2048 + h * 128;
        float x1 = base[j], x2 = base[j + 64];
        base[j]      = x1 * c - x2 * s;
        base[j + 64] = x2 * c + x1 * s;
    }
    {
        int h = tid >> 6;
        float* base = k + (size_t)t * 512 + h * 128;
        float x1 = base[j], x2 = base[j + 64];
        base[j]      = x1 * c - x2 * s;
        base[j + 64] = x2 * c + x1 * s;
    }
}

// ---------------------------------------------------------------------------
// MFMA flash attention (bf16 mfma_f32_16x16x32, f32 accum/softmax).
// Same as R1 except the output is written as bf16 (o-proj A operand).
// ---------------------------------------------------------------------------
__global__ __launch_bounds__(256) void attn_mfma(
    const float* __restrict__ q, const float* __restrict__ k,
    const float* __restrict__ v, short* __restrict__ out)
{
    __shared__ __align__(16) short Ks[64 * 128];   // bf16, XOR-swizzled rows
    __shared__ __align__(16) short Vt[128 * 72];   // bf16, transposed V, pad stride 72
    __shared__ __align__(16) short Pl[4][16 * 64]; // per-wave P, XOR-swizzled

    const int tid = threadIdx.x;
    const int l   = tid & 63;
    const int w   = tid >> 6;
    const int l15 = l & 15;
    const int l4  = l >> 4;
    const int h   = blockIdx.y;
    const int kvh = h >> 2;
    const int qb  = (TSEQ / 64 - 1) - blockIdx.x;  // heavy blocks first
    const int q0  = qb * 64;

    s8v qf[4];
    {
        const float* qrow = q + (size_t)(q0 + w * 16 + l15) * 2048 + h * 128;
        #pragma unroll
        for (int dc = 0; dc < 4; ++dc) {
            const int c0 = dc * 32 + l4 * 8;
            s8v f;
            #pragma unroll
            for (int j = 0; j < 8; ++j) f[j] = f2bf(qrow[c0 + j] * SCALING);
            qf[dc] = f;
        }
    }

    f4 o[8];
    #pragma unroll
    for (int dt = 0; dt < 8; ++dt) o[dt] = (f4){0.f, 0.f, 0.f, 0.f};
    float m[4]    = {-1e30f, -1e30f, -1e30f, -1e30f};
    float lsum[4] = {0.f, 0.f, 0.f, 0.f};

    const int nchunks = qb + 1;
    for (int kc = 0; kc < nchunks; ++kc) {
        const int k0 = kc * 64;
        __syncthreads();
        #pragma unroll
        for (int n = 0; n < 8; ++n) {
            int f = tid + 256 * n;
            int r = f >> 5, c4 = f & 31;
            f4 xv = *(const f4*)(k + (size_t)(k0 + r) * 512 + kvh * 128 + c4 * 4);
            s4v b;
            #pragma unroll
            for (int j = 0; j < 4; ++j) b[j] = f2bf(xv[j]);
            *(s4v*)(&Ks[(r * 128 + c4 * 4) ^ ((r & 7) << 3)]) = b;
        }
        #pragma unroll
        for (int n = 0; n < 2; ++n) {
            int bi = tid + 256 * n;
            int rb = bi & 15, cb = bi >> 4;
            const float* vb = v + (size_t)(k0 + rb * 4) * 512 + kvh * 128 + cb * 4;
            f4 r0 = *(const f4*)(vb);
            f4 r1 = *(const f4*)(vb + 512);
            f4 r2 = *(const f4*)(vb + 1024);
            f4 r3 = *(const f4*)(vb + 1536);
            #pragma unroll
            for (int j = 0; j < 4; ++j) {
                s4v c;
                c[0] = f2bf(r0[j]); c[1] = f2bf(r1[j]);
                c[2] = f2bf(r2[j]); c[3] = f2bf(r3[j]);
                *(s4v*)(&Vt[(cb * 4 + j) * 72 + rb * 4]) = c;
            }
        }
        __syncthreads();

        int kcm = 2, ntc = 4;
        if (kc == qb) { kcm = (w >= 2) ? 2 : 1; ntc = 2 * kcm; }

        f4 sA[4];
        #pragma unroll
        for (int nt = 0; nt < 4; ++nt) {
            if (nt < ntc) {
                f4 acc = (f4){0.f, 0.f, 0.f, 0.f};
                #pragma unroll
                for (int dc = 0; dc < 4; ++dc) {
                    s8v kf = *(const s8v*)(
                        &Ks[((nt * 16 + l15) * 128 + dc * 32 + l4 * 8) ^ ((l15 & 7) << 3)]);
                    acc = __builtin_amdgcn_mfma_f32_16x16x32_bf16(qf[dc], kf, acc, 0, 0, 0);
                }
                sA[nt] = acc;
            } else {
                sA[nt] = (f4){-1e30f, -1e30f, -1e30f, -1e30f};
            }
        }
        if (kc == qb) {
            #pragma unroll
            for (int nt = 0; nt < 4; ++nt)
                #pragma unroll
                for (int r = 0; r < 4; ++r)
                    if (nt * 16 + l15 > w * 16 + l4 * 4 + r) sA[nt][r] = -1e30f;
        }

        float scale_[4];
        #pragma unroll
        for (int r = 0; r < 4; ++r) {
            float mr = fmaxf(fmaxf(sA[0][r], sA[1][r]), fmaxf(sA[2][r], sA[3][r]));
            #pragma unroll
            for (int msk = 1; msk < 16; msk <<= 1)
                mr = fmaxf(mr, __shfl_xor(mr, msk, 64));
            float mn = fmaxf(m[r], mr);
            scale_[r] = exp2f((m[r] - mn) * LOG2E);
            m[r] = mn;
        }
        float ps[4] = {0.f, 0.f, 0.f, 0.f};
        f4 pv[4];
        #pragma unroll
        for (int nt = 0; nt < 4; ++nt) {
            #pragma unroll
            for (int r = 0; r < 4; ++r) {
                float p = exp2f((sA[nt][r] - m[r]) * LOG2E);
                pv[nt][r] = p;
                ps[r] += p;
            }
        }
        #pragma unroll
        for (int r = 0; r < 4; ++r) {
            float s_ = ps[r];
            #pragma unroll
            for (int msk = 1; msk < 16; msk <<= 1)
                s_ += __shfl_xor(s_, msk, 64);
            lsum[r] = lsum[r] * scale_[r] + s_;
        }
        #pragma unroll
        for (int nt = 0; nt < 4; ++nt) {
            if (nt < ntc) {
                #pragma unroll
                for (int r = 0; r < 4; ++r) {
                    int row = l4 * 4 + r, col = nt * 16 + l15;
                    Pl[w][(row * 64 + col) ^ ((row & 7) << 3)] = f2bf(pv[nt][r]);
                }
            }
        }
        #pragma unroll
        for (int dt = 0; dt < 8; ++dt)
            #pragma unroll
            for (int r = 0; r < 4; ++r) o[dt][r] *= scale_[r];
        #pragma unroll
        for (int kcc = 0; kcc < 2; ++kcc) {
            if (kcc < kcm) {
                s8v pf = *(const s8v*)(
                    &Pl[w][(l15 * 64 + kcc * 32 + l4 * 8) ^ ((l15 & 7) << 3)]);
                #pragma unroll
                for (int dt = 0; dt < 8; ++dt) {
                    s8v vf = *(const s8v*)(&Vt[(dt * 16 + l15) * 72 + kcc * 32 + l4 * 8]);
                    o[dt] = __builtin_amdgcn_mfma_f32_16x16x32_bf16(pf, vf, o[dt], 0, 0, 0);
                }
            }
        }
    }

    float inv[4];
    #pragma unroll
    for (int r = 0; r < 4; ++r) inv[r] = 1.0f / lsum[r];
    #pragma unroll
    for (int dt = 0; dt < 8; ++dt)
        #pragma unroll
        for (int r = 0; r < 4; ++r)
            out[(size_t)(q0 + w * 16 + l4 * 4 + r) * 2048 + h * 128 + dt * 16 + l15] =
                f2bf(o[dt][r] * inv[r]);
}

// ---------------------------------------------------------------------------
extern "C" void kernel_launch(void* const* d_in, const int* in_sizes, int n_in,
                              void* d_out, int out_size, void* d_ws, size_t ws_size,
                              hipStream_t stream)
{
    const int*   positions = (const int*)  d_in[0];
    const float* hidden    = (const float*)d_in[1];
    const int*   q_qw = (const int*)  d_in[2];
    const float* q_sc = (const float*)d_in[3];
    const int*   q_zr = (const int*)  d_in[4];
    const int*   k_qw = (const int*)  d_in[5];
    const float* k_sc = (const float*)d_in[6];
    const int*   k_zr = (const int*)  d_in[7];
    const int*   v_qw = (const int*)  d_in[8];
    const float* v_sc = (const float*)d_in[9];
    const int*   v_zr = (const int*)  d_in[10];
    const int*   o_qw = (const int*)  d_in[11];
    const float* o_sc = (const float*)d_in[12];
    const int*   o_zr = (const int*)  d_in[13];
    float* outf = (float*)d_out;

    // workspace: q f32[T,2048] | k f32[T,512] | v f32[T,512] | abuf bf16[T,2048]
    //            | hb bf16[2048,2048]   (16+4+4+8+8 = 40 MB)
    float* qbuf = (float*)d_ws;
    float* kbuf = qbuf + (size_t)TSEQ * 2048;
    float* vbuf = kbuf + (size_t)TSEQ * 512;
    short* abuf = (short*)(vbuf + (size_t)TSEQ * 512);
    short* hb   = abuf + (size_t)TSEQ * 2048;

    dim3 blk(256);
    f32_to_bf16<<<dim3(2048), blk, 0, stream>>>(hidden, hb);
    gemm_gptq_mfma<128, 64><<<dim3(32, 16), blk, 0, stream>>>(hb, q_qw, q_sc, q_zr, qbuf, 2048);
    gemm_gptq_mfma<64, 64><<<dim3(8, 32),  blk, 0, stream>>>(hb, k_qw, k_sc, k_zr, kbuf, 512);
    gemm_gptq_mfma<64, 64><<<dim3(8, 32),  blk, 0, stream>>>(hb, v_qw, v_sc, v_zr, vbuf, 512);
    rope_kernel<<<dim3(TSEQ), blk, 0, stream>>>(positions, qbuf, kbuf);
    attn_mfma<<<dim3(TSEQ / 64, NH), blk, 0, stream>>>(qbuf, kbuf, vbuf, abuf);
    gemm_gptq_mfma<128, 64><<<dim3(32, 16), blk, 0, stream>>>(abuf, o_qw, o_sc, o_zr, outf, 2048);
}